// Round 7
// baseline (516.535 us; speedup 1.0000x reference)
//
#include <hip/hip_runtime.h>

// ---- problem constants (from reference) ----
#define N_LANEC  20000
#define N_AGENTC 4000
#define PTS      20
#define FD       8
#define HD       128
#define E_LLC    640000
#define E_AAC    128000
#define E_LAC    200000

typedef unsigned short u16;
typedef unsigned int   u32;
typedef __attribute__((ext_vector_type(8))) short short8;   // 8 bf16 (4 VGPRs)
typedef __attribute__((ext_vector_type(4))) float f32x4;    // MFMA C/D

__device__ __forceinline__ float bf2f(u16 u) {
    union { u32 i; float f; } c; c.i = ((u32)u) << 16; return c.f;
}
__device__ __forceinline__ u16 f2bf(float f) {
    union { float f; u32 i; } c; c.f = f;
    u32 r = c.i + 0x7FFFu + ((c.i >> 16) & 1u);   // RNE
    return (u16)(r >> 16);
}
__device__ __forceinline__ float ldf(const void* p, size_t i, int isf) {
    return isf ? ((const float*)p)[i] : bf2f(((const u16*)p)[i]);
}

// ---------------------------------------------------------------------------
// input dtype detection (bf16 vs fp32) — round-4 verified (chose fp32)
// ---------------------------------------------------------------------------
__global__ void detect_kernel(const u32* __restrict__ x, int* __restrict__ flag) {
    __shared__ int cnt;
    if (threadIdx.x == 0) cnt = 0;
    __syncthreads();
    u32 w = x[threadIdx.x];
    int e = (int)((w >> 7) & 0xFFu);
    int ok = (e == 0) || (e >= 100 && e <= 140);
    atomicAdd(&cnt, ok);
    __syncthreads();
    if (threadIdx.x == 0) *flag = (cnt >= 200) ? 0 : 1;   // 1 = fp32 inputs
}

// ---------------------------------------------------------------------------
// Fused weight swizzle (10 matrices) to MFMA B-frag-major bf16:
// dst[((nt*KS+ks)*64+lane)*8+j] = bf16(src[(ks*32+(lane>>4)*8+j)*128 + nt*16+(lane&15)])
// ---------------------------------------------------------------------------
struct SwzSrc { const void* p[10]; };
#define SWZ_TOTAL 212992
__global__ __launch_bounds__(256) void swz_all_kernel(
    SwzSrc s, u16* __restrict__ dst, const int* __restrict__ dflag)
{
    const int sizes[10] = {16384,16384,16384,16384,32768,16384,32768,16384,32768,16384};
    const int kss[10]   = {2,2,2,2,3,2,3,2,3,2};
    const int isf = *dflag;
    int idx = blockIdx.x * 256 + threadIdx.x;
    if (idx >= SWZ_TOTAL) return;
    int seg = 0, rem = idx;
    while (rem >= sizes[seg]) { rem -= sizes[seg]; seg++; }
    int kshift = kss[seg];
    int j    = rem & 7;
    int lane = (rem >> 3) & 63;
    int t2   = rem >> 9;
    int ks   = t2 & ((1 << kshift) - 1);
    int nt   = t2 >> kshift;
    int k = ks * 32 + ((lane >> 4) << 3) + j;
    int n = nt * 16 + (lane & 15);
    dst[idx] = f2bf(ldf(s.p[seg], (size_t)k * HD + n, isf));
}

// ---------------------------------------------------------------------------
// PointNet encoder: x[n][20][8] -> out[n][128] bf16. 4 nodes/block, 4 waves.
// L1: VALU -> a_lds(bf16). L2: MFMA + atomicMax(max-over-t) epilogue.
// L3: MFMA on ms (M=4 rows, rest zero). LDS ~31 KB (5 blocks/CU).
// ---------------------------------------------------------------------------
__global__ __launch_bounds__(256) void encode_kernel(
    const void* __restrict__ x,
    const void* __restrict__ w1, const void* __restrict__ b1,
    const u16* __restrict__ w2s, const void* __restrict__ b2,
    const u16* __restrict__ w3s, const void* __restrict__ b3,
    u16* __restrict__ out, const int* __restrict__ dflag)
{
    const int NT = 4;                                  // nodes/block, M = 80
    __shared__ float xs[NT][PTS][FD];
    __shared__ float refs[NT][2];
    __shared__ __align__(16) u16 a_lds[NT * PTS][HD + 8];  // h1 bf16
    __shared__ int msI[NT][HD];                        // max-over-t, fp32 bits
    __shared__ __align__(16) u16 msb[16][HD + 8];      // ms bf16, rows 4..15 = 0

    const int isf = *dflag;
    const int tid  = threadIdx.x;
    const int lane = tid & 63;
    const int wv   = tid >> 6;
    const int l15  = lane & 15;
    const int quad = lane >> 4;
    const int j = tid & (HD - 1);
    const int g = tid >> 7;
    const int n0 = blockIdx.x * NT;

    // zero ms buffers (consumed after later barriers)
    for (int idx = tid; idx < NT * HD; idx += 256) ((int*)msI)[idx] = 0;
    for (int idx = tid; idx < 16 * (HD + 8) / 2; idx += 256) ((u32*)msb)[idx] = 0;

    // ---- stage x, subtract last-point xy ref ----
    float* xsf = &xs[0][0][0];
    for (int idx = tid; idx < NT * PTS * FD; idx += 256)
        xsf[idx] = ldf(x, (size_t)n0 * PTS * FD + idx, isf);
    __syncthreads();
    if (tid < NT * 2) refs[tid >> 1][tid & 1] = xs[tid >> 1][PTS - 1][tid & 1];
    __syncthreads();
    for (int idx = tid; idx < NT * PTS * 2; idx += 256) {
        int nn = idx / (PTS * 2); int r = idx - nn * PTS * 2;
        xs[nn][r >> 1][r & 1] -= refs[nn][r & 1];
    }
    __syncthreads();

    // ---- layer 1 (K=8), VALU -> a_lds bf16 ----
    float w1c[FD];
    #pragma unroll
    for (int k = 0; k < FD; k++) w1c[k] = ldf(w1, k * HD + j, isf);
    const float b1j = ldf(b1, j, isf);
    float acc[2][PTS];
    #pragma unroll
    for (int nn = 0; nn < 2; nn++)
        #pragma unroll
        for (int t = 0; t < PTS; t++) acc[nn][t] = b1j;
    #pragma unroll
    for (int k = 0; k < FD; k++) {
        float w = w1c[k];
        #pragma unroll
        for (int nn = 0; nn < 2; nn++)
            #pragma unroll
            for (int t = 0; t < PTS; t++)
                acc[nn][t] += xs[g * 2 + nn][t][k] * w;
    }
    #pragma unroll
    for (int nn = 0; nn < 2; nn++)
        #pragma unroll
        for (int t = 0; t < PTS; t++)
            a_lds[(g * 2 + nn) * PTS + t][j] = f2bf(fmaxf(acc[nn][t], 0.f));
    __syncthreads();

    // ---- layer 2: MFMA; epilogue folds relu+max-over-t via LDS atomicMax ----
    short8 bfr[2][4];
    float b2v[2];
    #pragma unroll
    for (int nt2 = 0; nt2 < 2; nt2++) {
        const int ntg = wv * 2 + nt2;
        b2v[nt2] = ldf(b2, ntg * 16 + l15, isf);
        #pragma unroll
        for (int ks = 0; ks < 4; ks++)
            bfr[nt2][ks] = *(const short8*)&w2s[(((size_t)(ntg * 4 + ks)) * 64 + lane) * 8];
    }
    for (int mt = 0; mt < 5; mt++) {
        short8 af[4];
        #pragma unroll
        for (int ks = 0; ks < 4; ks++)
            af[ks] = *(const short8*)&a_lds[mt * 16 + l15][ks * 32 + quad * 8];
        #pragma unroll
        for (int nt2 = 0; nt2 < 2; nt2++) {
            f32x4 c = {0.f, 0.f, 0.f, 0.f};
            #pragma unroll
            for (int ks = 0; ks < 4; ks++)
                c = __builtin_amdgcn_mfma_f32_16x16x32_bf16(af[ks], bfr[nt2][ks], c, 0, 0, 0);
            const int col = (wv * 2 + nt2) * 16 + l15;
            #pragma unroll
            for (int r = 0; r < 4; r++) {
                const int m = mt * 16 + quad * 4 + r;
                const int node = m / PTS;              // 0..3
                const float v = fmaxf(c[r] + b2v[nt2], 0.f);
                atomicMax(&msI[node][col], __float_as_int(v));  // v>=0: int order ok
            }
        }
    }
    __syncthreads();

    // ---- ms -> bf16 A-layout (rows 0..3; 4..15 stay zero) ----
    // FIX(r6->r7): strided loop — NT*HD=512 > blockDim=256; the old
    // `if (tid < NT*HD)` left nodes 2..3 zeroed (absmax 6.8 failure).
    for (int idx = tid; idx < NT * HD; idx += 256)
        msb[idx >> 7][idx & 127] = f2bf(__int_as_float(((int*)msI)[idx]));
    __syncthreads();

    // ---- layer 3: MFMA (M=4 live rows) ----
    #pragma unroll
    for (int nt2 = 0; nt2 < 2; nt2++) {
        const int ntg = wv * 2 + nt2;
        const float b3v = ldf(b3, ntg * 16 + l15, isf);
        f32x4 c = {0.f, 0.f, 0.f, 0.f};
        #pragma unroll
        for (int ks = 0; ks < 4; ks++) {
            short8 a = *(const short8*)&msb[l15][ks * 32 + quad * 8];
            short8 b = *(const short8*)&w3s[(((size_t)(ntg * 4 + ks)) * 64 + lane) * 8];
            c = __builtin_amdgcn_mfma_f32_16x16x32_bf16(a, b, c, 0, 0, 0);
        }
        #pragma unroll
        for (int r = 0; r < 4; r++) {
            const int row = quad * 4 + r;
            if (row < NT)
                out[(size_t)(n0 + row) * HD + ntg * 16 + l15] = f2bf(fmaxf(c[r] + b3v, 0.f));
        }
    }
}

// ---------------------------------------------------------------------------
// Fused aggregation + edge-GNN MLP.
// Phase A: wave-per-node mean-gather (shfl-broadcast cols, u32/float2 rows).
// Phase B: MFMA MLP, out = node + relu(relu([node,agg]@w1+b1)@w2+b2).
// out buffer must differ from gather source; residual reads own rows only.
// ---------------------------------------------------------------------------
template<int SRC_F32, int OUT_BF16>
__global__ __launch_bounds__(256) void gnn_kernel(
    const u16* __restrict__ node, const void* __restrict__ srcv,
    const u16* __restrict__ col, const int* __restrict__ rowptr,
    const u16* __restrict__ w1s, const void* __restrict__ b1,
    const u16* __restrict__ w2s, const void* __restrict__ b2,
    void* __restrict__ outv, const int* __restrict__ dflag)
{
    __shared__ __align__(16) u16 cats[16][2 * HD + 8];
    __shared__ __align__(16) u16 hb[16][HD + 8];
    const int isf = *dflag;
    const int tid  = threadIdx.x;
    const int lane = tid & 63;
    const int wv   = tid >> 6;
    const int l15  = lane & 15;
    const int quad = lane >> 4;
    const int n0 = blockIdx.x * 16;

    // node halves of cats (u32 = 2 bf16)
    const u32* node32 = (const u32*)node;
    for (int idx = tid; idx < 16 * 64; idx += 256) {
        int nn = idx >> 6, k2 = idx & 63;
        *(u32*)&cats[nn][k2 * 2] = node32[(size_t)(n0 + nn) * 64 + k2];
    }
    // mean aggregation: wave wv -> nodes wv*4 .. wv*4+3
    for (int q = 0; q < 4; q++) {
        const int dn = wv * 4 + q;
        const int d = n0 + dn;
        const int beg = rowptr[d], end = rowptr[d + 1];
        float a0 = 0.f, a1 = 0.f;
        for (int base = beg; base < end; base += 64) {
            const int m = min(64, end - base);
            int cv = (lane < m) ? (int)col[base + lane] : 0;
            for (int i = 0; i < m; i++) {
                int ridx = __shfl(cv, i, 64);
                if (SRC_F32) {
                    float2 v = ((const float2*)srcv)[(size_t)ridx * 64 + lane];
                    a0 += v.x; a1 += v.y;
                } else {
                    u32 v = ((const u32*)srcv)[(size_t)ridx * 64 + lane];
                    a0 += bf2f((u16)v); a1 += bf2f((u16)(v >> 16));
                }
            }
        }
        const float inv = 1.f / fmaxf((float)(end - beg), 1.f);
        *(u32*)&cats[dn][HD + lane * 2] =
            ((u32)f2bf(a1 * inv) << 16) | (u32)f2bf(a0 * inv);
    }
    __syncthreads();

    // ---- layer 1: K=256 ----
    #pragma unroll
    for (int nt2 = 0; nt2 < 2; nt2++) {
        const int ntg = wv * 2 + nt2;
        const float b1v = ldf(b1, ntg * 16 + l15, isf);
        f32x4 c = {0.f, 0.f, 0.f, 0.f};
        #pragma unroll
        for (int ks = 0; ks < 8; ks++) {
            short8 a = *(const short8*)&cats[l15][ks * 32 + quad * 8];
            short8 b = *(const short8*)&w1s[(((size_t)(ntg * 8 + ks)) * 64 + lane) * 8];
            c = __builtin_amdgcn_mfma_f32_16x16x32_bf16(a, b, c, 0, 0, 0);
        }
        #pragma unroll
        for (int r = 0; r < 4; r++)
            hb[quad * 4 + r][ntg * 16 + l15] = f2bf(fmaxf(c[r] + b1v, 0.f));
    }
    __syncthreads();

    // ---- layer 2: K=128, residual epilogue ----
    #pragma unroll
    for (int nt2 = 0; nt2 < 2; nt2++) {
        const int ntg = wv * 2 + nt2;
        const float b2v = ldf(b2, ntg * 16 + l15, isf);
        f32x4 c = {0.f, 0.f, 0.f, 0.f};
        #pragma unroll
        for (int ks = 0; ks < 4; ks++) {
            short8 a = *(const short8*)&hb[l15][ks * 32 + quad * 8];
            short8 b = *(const short8*)&w2s[(((size_t)(ntg * 4 + ks)) * 64 + lane) * 8];
            c = __builtin_amdgcn_mfma_f32_16x16x32_bf16(a, b, c, 0, 0, 0);
        }
        #pragma unroll
        for (int r = 0; r < 4; r++) {
            const int row = quad * 4 + r;
            const int cidx = ntg * 16 + l15;
            size_t o = (size_t)(n0 + row) * HD + cidx;
            float res = bf2f(node[o]) + fmaxf(c[r] + b2v, 0.f);
            if (OUT_BF16) ((u16*)outv)[o] = f2bf(res);
            else          ((float*)outv)[o] = res;
        }
    }
}

// ---------------------------------------------------------------------------
// CSR build: zero, fused count, scan (emits cursors), fused fill
// ---------------------------------------------------------------------------
__global__ void zero_kernel(int* __restrict__ p, int n) {
    int i = blockIdx.x * blockDim.x + threadIdx.x;
    if (i < n) p[i] = 0;
}
__global__ void count_all_kernel(const int* __restrict__ e_ll, const int* __restrict__ e_aa,
                                 const int* __restrict__ e_la,
                                 int* __restrict__ rp_ll, int* __restrict__ rp_aa,
                                 int* __restrict__ rp_la) {
    int e = blockIdx.x * blockDim.x + threadIdx.x;
    if (e < E_LLC) atomicAdd(&rp_ll[e_ll[E_LLC + e]], 1);
    else if (e < E_LLC + E_AAC) atomicAdd(&rp_aa[e_aa[E_AAC + (e - E_LLC)]], 1);
    else if (e < E_LLC + E_AAC + E_LAC) atomicAdd(&rp_la[e_la[E_LAC + (e - E_LLC - E_AAC)]], 1);
}
__global__ void fill_all_kernel(const int* __restrict__ e_ll, const int* __restrict__ e_aa,
                                const int* __restrict__ e_la, int* __restrict__ cur,
                                u16* __restrict__ col_ll, u16* __restrict__ col_aa,
                                u16* __restrict__ col_la) {
    int e = blockIdx.x * blockDim.x + threadIdx.x;
    if (e < E_LLC) {
        int p = atomicAdd(&cur[e_ll[E_LLC + e]], 1);
        col_ll[p] = (u16)e_ll[e];
    } else if (e < E_LLC + E_AAC) {
        int i = e - E_LLC;
        int p = atomicAdd(&cur[N_LANEC + e_aa[E_AAC + i]], 1);
        col_aa[p] = (u16)e_aa[i];
    } else if (e < E_LLC + E_AAC + E_LAC) {
        int i = e - E_LLC - E_AAC;
        int p = atomicAdd(&cur[N_LANEC + N_AGENTC + e_la[E_LAC + i]], 1);
        col_la[p] = (u16)e_la[i];
    }
}

// in-place exclusive scan (LDS Hillis-Steele); also emits cursor copies
__global__ __launch_bounds__(1024) void scan3_kernel(
    int* __restrict__ rp_ll, int* __restrict__ rp_aa, int* __restrict__ rp_la,
    int* __restrict__ cur)
{
    int* rp; int n; int coff;
    if (blockIdx.x == 0)      { rp = rp_ll; n = N_LANEC; coff = 0; }
    else if (blockIdx.x == 1) { rp = rp_aa; n = N_AGENTC; coff = N_LANEC; }
    else                      { rp = rp_la; n = N_AGENTC; coff = N_LANEC + N_AGENTC; }

    __shared__ int s[1024];
    __shared__ int carry;
    const int tid = threadIdx.x;
    if (tid == 0) carry = 0;
    __syncthreads();

    for (int base = 0; base < n; base += 1024) {
        const int i = base + tid;
        const int v = (i < n) ? rp[i] : 0;
        s[tid] = v;
        __syncthreads();
        for (int off = 1; off < 1024; off <<= 1) {
            int t = (tid >= off) ? s[tid - off] : 0;
            __syncthreads();
            s[tid] += t;
            __syncthreads();
        }
        const int incl = s[tid];
        const int c = carry;
        __syncthreads();
        if (i < n) { int ex = c + incl - v; rp[i] = ex; cur[coff + i] = ex; }
        if (tid == 1023) carry = c + incl;
        __syncthreads();
    }
    if (tid == 0) rp[n] = carry;
}

// ---------------------------------------------------------------------------
extern "C" void kernel_launch(void* const* d_in, const int* in_sizes, int n_in,
                              void* d_out, int out_size, void* d_ws, size_t ws_size,
                              hipStream_t stream)
{
    const void* lane_pts   = d_in[0];
    const void* agent_hist = d_in[1];
    const int* e_ll = (const int*)d_in[2];   // [2][E]: row0 src, row1 dst
    const int* e_aa = (const int*)d_in[3];
    const int* e_la = (const int*)d_in[4];
    const void *lw1 = d_in[5],  *lb1 = d_in[6],  *lw2 = d_in[7],  *lb2 = d_in[8],
               *lw3 = d_in[9],  *lb3 = d_in[10];
    const void *aw1 = d_in[11], *ab1 = d_in[12], *aw2 = d_in[13], *ab2 = d_in[14],
               *aw3 = d_in[15], *ab3 = d_in[16];
    const void *llw1 = d_in[17], *llb1 = d_in[18], *llw2 = d_in[19], *llb2 = d_in[20];
    const void *aaw1 = d_in[21], *aab1 = d_in[22], *aaw2 = d_in[23], *aab2 = d_in[24];
    const void *law1 = d_in[25], *lab1 = d_in[26], *law2 = d_in[27], *lab2 = d_in[28];

    // ---- workspace layout (~9.8 MB) ----
    u16* sp = (u16*)d_ws;
    u16* swzbase = sp; sp += SWZ_TOTAL;      // 10 swizzled matrices
    u16* lw2s  = swzbase + 0;
    u16* aw2s  = swzbase + 16384;
    u16* lw3s  = swzbase + 32768;
    u16* aw3s  = swzbase + 49152;
    u16* llw1s = swzbase + 65536;
    u16* llw2s = swzbase + 98304;
    u16* aaw1s = swzbase + 114688;
    u16* aaw2s = swzbase + 147456;
    u16* law1s = swzbase + 163840;
    u16* law2s = swzbase + 196608;
    int* ip = (int*)sp;
    int* dflag = ip; ip += 4;
    int* rp_ll = ip; ip += N_LANEC + 1;
    int* rp_aa = ip; ip += N_AGENTC + 1;
    int* rp_la = ip; ip += N_AGENTC + 1;
    int* cur   = ip; ip += N_LANEC + 2 * N_AGENTC;
    u16* hp = (u16*)ip;
    u16* col_ll = hp; hp += E_LLC;
    u16* col_aa = hp; hp += E_AAC;
    u16* col_la = hp; hp += E_LAC;
    u16* lane_enc  = hp; hp += (size_t)N_LANEC * HD;
    u16* agent_enc = hp; hp += (size_t)N_AGENTC * HD;
    u16* agent_mid = hp; hp += (size_t)N_AGENTC * HD;

    float* out_lane  = (float*)d_out;
    float* out_agent = (float*)d_out + (size_t)N_LANEC * HD;

    const int NRP = (N_LANEC + 1) + 2 * (N_AGENTC + 1);
    const int NE_TOT = E_LLC + E_AAC + E_LAC;

    detect_kernel<<<1, 256, 0, stream>>>((const u32*)lane_pts, dflag);

    SwzSrc ss;
    ss.p[0] = lw2;  ss.p[1] = aw2;  ss.p[2] = lw3;  ss.p[3] = aw3;
    ss.p[4] = llw1; ss.p[5] = llw2; ss.p[6] = aaw1; ss.p[7] = aaw2;
    ss.p[8] = law1; ss.p[9] = law2;
    swz_all_kernel<<<(SWZ_TOTAL + 255) / 256, 256, 0, stream>>>(ss, swzbase, dflag);

    // ---- CSR build ----
    zero_kernel<<<(NRP + 255) / 256, 256, 0, stream>>>(rp_ll, NRP);
    count_all_kernel<<<(NE_TOT + 255) / 256, 256, 0, stream>>>(e_ll, e_aa, e_la, rp_ll, rp_aa, rp_la);
    scan3_kernel<<<3, 1024, 0, stream>>>(rp_ll, rp_aa, rp_la, cur);
    fill_all_kernel<<<(NE_TOT + 255) / 256, 256, 0, stream>>>(e_ll, e_aa, e_la, cur, col_ll, col_aa, col_la);

    // ---- encoders ----
    encode_kernel<<<N_LANEC / 4, 256, 0, stream>>>(lane_pts, lw1, lb1, lw2s, lb2, lw3s, lb3, lane_enc, dflag);
    encode_kernel<<<N_AGENTC / 4, 256, 0, stream>>>(agent_hist, aw1, ab1, aw2s, ab2, aw3s, ab3, agent_enc, dflag);

    // ---- lane-lane: gather from lane_enc, out fp32 -> d_out lane ----
    gnn_kernel<0, 0><<<N_LANEC / 16, 256, 0, stream>>>(
        lane_enc, lane_enc, col_ll, rp_ll, llw1s, llb1, llw2s, llb2, out_lane, dflag);

    // ---- agent-agent: gather from agent_enc, out bf16 -> agent_mid ----
    gnn_kernel<0, 1><<<N_AGENTC / 16, 256, 0, stream>>>(
        agent_enc, agent_enc, col_aa, rp_aa, aaw1s, aab1, aaw2s, aab2, agent_mid, dflag);

    // ---- lane->agent: gather fp32 from final lane, node=agent_mid,
    //      out fp32 -> d_out agent ----
    gnn_kernel<1, 0><<<N_AGENTC / 16, 256, 0, stream>>>(
        agent_mid, out_lane, col_la, rp_la, law1s, lab1, law2s, lab2, out_agent, dflag);
}

// Round 8
// 379.292 us; speedup vs baseline: 1.3618x; 1.3618x over previous
//
#include <hip/hip_runtime.h>

// ---- problem constants (from reference) ----
#define N_LANEC  20000
#define N_AGENTC 4000
#define PTS      20
#define FD       8
#define HD       128
#define E_LLC    640000
#define E_AAC    128000
#define E_LAC    200000

typedef unsigned short u16;
typedef unsigned int   u32;
typedef __attribute__((ext_vector_type(8))) short short8;   // 8 bf16 (4 VGPRs)
typedef __attribute__((ext_vector_type(4))) float f32x4;    // MFMA C/D

__device__ __forceinline__ float bf2f(u16 u) {
    union { u32 i; float f; } c; c.i = ((u32)u) << 16; return c.f;
}
__device__ __forceinline__ u16 f2bf(float f) {
    union { float f; u32 i; } c; c.f = f;
    u32 r = c.i + 0x7FFFu + ((c.i >> 16) & 1u);   // RNE
    return (u16)(r >> 16);
}
__device__ __forceinline__ float ldf(const void* p, size_t i, int isf) {
    return isf ? ((const float*)p)[i] : bf2f(((const u16*)p)[i]);
}

// ---------------------------------------------------------------------------
// input dtype detection (bf16 vs fp32) — round-4 verified (chose fp32)
// ---------------------------------------------------------------------------
__global__ void detect_kernel(const u32* __restrict__ x, int* __restrict__ flag) {
    __shared__ int cnt;
    if (threadIdx.x == 0) cnt = 0;
    __syncthreads();
    u32 w = x[threadIdx.x];
    int e = (int)((w >> 7) & 0xFFu);
    int ok = (e == 0) || (e >= 100 && e <= 140);
    atomicAdd(&cnt, ok);
    __syncthreads();
    if (threadIdx.x == 0) *flag = (cnt >= 200) ? 0 : 1;   // 1 = fp32 inputs
}

// ---------------------------------------------------------------------------
// Fused weight prep: segs 0..9 = MFMA B-frag swizzle (128xHD / 256xHD mats),
// segs 10..23 = plain fp32/bf16 -> bf16 linear conversion (w1s, biases).
// Swizzle: dst[((nt*KS+ks)*64+lane)*8+j] =
//          bf16(src[(ks*32+(lane>>4)*8+j)*HD + nt*16+(lane&15)])
// ---------------------------------------------------------------------------
struct SwzSrc { const void* p[24]; };
#define SWZ_MAT_TOTAL 212992
#define SWZ_TOTAL     216576
__global__ __launch_bounds__(256) void swz_all_kernel(
    SwzSrc s, u16* __restrict__ dst, const int* __restrict__ dflag)
{
    const int sizes[24] = {16384,16384,16384,16384,32768,16384,32768,16384,32768,16384,
                           1024,1024, 128,128,128,128,128,128,128,128,128,128,128,128};
    const int kss[10]   = {2,2,2,2,3,2,3,2,3,2};
    const int isf = *dflag;
    int idx = blockIdx.x * 256 + threadIdx.x;
    if (idx >= SWZ_TOTAL) return;
    int seg = 0, rem = idx;
    while (rem >= sizes[seg]) { rem -= sizes[seg]; seg++; }
    if (seg >= 10) {                       // linear convert
        dst[idx] = f2bf(ldf(s.p[seg], rem, isf));
        return;
    }
    int kshift = kss[seg];
    int j    = rem & 7;
    int lane = (rem >> 3) & 63;
    int t2   = rem >> 9;
    int ks   = t2 & ((1 << kshift) - 1);
    int nt   = t2 >> kshift;
    int k = ks * 32 + ((lane >> 4) << 3) + j;
    int n = nt * 16 + (lane & 15);
    dst[idx] = f2bf(ldf(s.p[seg], (size_t)k * HD + n, isf));
}

// ---------------------------------------------------------------------------
// Merged PointNet encoders (lane blocks 0..4999, agent 5000..5999).
// L1: VALU -> a_lds(bf16). L2: MFMA + atomicMax max-over-t. L3: MFMA.
// All weights/biases pre-converted bf16. LDS ~31 KB (5 blocks/CU).
// ---------------------------------------------------------------------------
struct EncArgs {
    const void* x0; const void* x1;
    const u16 *w1a, *b1a, *w2a, *b2a, *w3a, *b3a;   // lane set
    const u16 *w1b, *b1b, *w2b, *b2b, *w3b, *b3b;   // agent set
    u16 *out0, *out1;
};
__global__ __launch_bounds__(256) void encode_kernel(EncArgs ea, const int* __restrict__ dflag)
{
    const int NT = 4;                                  // nodes/block, M = 80
    __shared__ __align__(16) float xs[NT][PTS][FD];
    __shared__ float refs[NT][2];
    __shared__ __align__(16) u16 a_lds[NT * PTS][HD + 8];  // h1 bf16
    __shared__ int msI[NT][HD];                        // max-over-t, fp32 bits
    __shared__ __align__(16) u16 msb[16][HD + 8];      // ms bf16, rows 4..15 = 0

    const int isf = *dflag;
    const int isLane = (blockIdx.x < N_LANEC / 4);
    const void* x   = isLane ? ea.x0 : ea.x1;
    const u16* w1 = isLane ? ea.w1a : ea.w1b;
    const u16* b1 = isLane ? ea.b1a : ea.b1b;
    const u16* w2s = isLane ? ea.w2a : ea.w2b;
    const u16* b2 = isLane ? ea.b2a : ea.b2b;
    const u16* w3s = isLane ? ea.w3a : ea.w3b;
    const u16* b3 = isLane ? ea.b3a : ea.b3b;
    u16* out = isLane ? ea.out0 : ea.out1;
    const int n0 = (isLane ? blockIdx.x : blockIdx.x - N_LANEC / 4) * NT;

    const int tid  = threadIdx.x;
    const int lane = tid & 63;
    const int wv   = tid >> 6;
    const int l15  = lane & 15;
    const int quad = lane >> 4;
    const int j = tid & (HD - 1);
    const int g = tid >> 7;

    // zero ms buffers (consumed after later barriers)
    for (int idx = tid; idx < NT * HD; idx += 256) ((int*)msI)[idx] = 0;
    for (int idx = tid; idx < 16 * (HD + 8) / 2; idx += 256) ((u32*)msb)[idx] = 0;

    // ---- stage x (vectorized fp32 fast path), subtract last-point xy ref ----
    float* xsf = &xs[0][0][0];
    if (isf) {
        const float4* x4 = (const float4*)x + (size_t)n0 * (PTS * FD / 4);
        float4* s4 = (float4*)xsf;
        for (int idx = tid; idx < NT * PTS * FD / 4; idx += 256) s4[idx] = x4[idx];
    } else {
        const u16* xb = (const u16*)x + (size_t)n0 * PTS * FD;
        for (int idx = tid; idx < NT * PTS * FD; idx += 256) xsf[idx] = bf2f(xb[idx]);
    }
    __syncthreads();
    if (tid < NT * 2) refs[tid >> 1][tid & 1] = xs[tid >> 1][PTS - 1][tid & 1];
    __syncthreads();
    for (int idx = tid; idx < NT * PTS * 2; idx += 256) {
        int nn = idx / (PTS * 2); int r = idx - nn * PTS * 2;
        xs[nn][r >> 1][r & 1] -= refs[nn][r & 1];
    }
    __syncthreads();

    // ---- layer 1 (K=8), VALU -> a_lds bf16 ----
    float w1c[FD];
    #pragma unroll
    for (int k = 0; k < FD; k++) w1c[k] = bf2f(w1[k * HD + j]);
    const float b1j = bf2f(b1[j]);
    float acc[2][PTS];
    #pragma unroll
    for (int nn = 0; nn < 2; nn++)
        #pragma unroll
        for (int t = 0; t < PTS; t++) acc[nn][t] = b1j;
    #pragma unroll
    for (int k = 0; k < FD; k++) {
        float w = w1c[k];
        #pragma unroll
        for (int nn = 0; nn < 2; nn++)
            #pragma unroll
            for (int t = 0; t < PTS; t++)
                acc[nn][t] += xs[g * 2 + nn][t][k] * w;
    }
    #pragma unroll
    for (int nn = 0; nn < 2; nn++)
        #pragma unroll
        for (int t = 0; t < PTS; t++)
            a_lds[(g * 2 + nn) * PTS + t][j] = f2bf(fmaxf(acc[nn][t], 0.f));
    __syncthreads();

    // ---- layer 2: MFMA; epilogue folds relu+max-over-t via LDS atomicMax ----
    short8 bfr[2][4];
    float b2v[2];
    #pragma unroll
    for (int nt2 = 0; nt2 < 2; nt2++) {
        const int ntg = wv * 2 + nt2;
        b2v[nt2] = bf2f(b2[ntg * 16 + l15]);
        #pragma unroll
        for (int ks = 0; ks < 4; ks++)
            bfr[nt2][ks] = *(const short8*)&w2s[(((size_t)(ntg * 4 + ks)) * 64 + lane) * 8];
    }
    for (int mt = 0; mt < 5; mt++) {
        short8 af[4];
        #pragma unroll
        for (int ks = 0; ks < 4; ks++)
            af[ks] = *(const short8*)&a_lds[mt * 16 + l15][ks * 32 + quad * 8];
        #pragma unroll
        for (int nt2 = 0; nt2 < 2; nt2++) {
            f32x4 c = {0.f, 0.f, 0.f, 0.f};
            #pragma unroll
            for (int ks = 0; ks < 4; ks++)
                c = __builtin_amdgcn_mfma_f32_16x16x32_bf16(af[ks], bfr[nt2][ks], c, 0, 0, 0);
            const int col = (wv * 2 + nt2) * 16 + l15;
            #pragma unroll
            for (int r = 0; r < 4; r++) {
                const int m = mt * 16 + quad * 4 + r;
                const int node = m / PTS;              // 0..3
                const float v = fmaxf(c[r] + b2v[nt2], 0.f);
                atomicMax(&msI[node][col], __float_as_int(v));  // v>=0: int order ok
            }
        }
    }
    __syncthreads();

    // ---- ms -> bf16 A-layout (rows 0..3; 4..15 stay zero); strided (r7 fix) ----
    for (int idx = tid; idx < NT * HD; idx += 256)
        msb[idx >> 7][idx & 127] = f2bf(__int_as_float(((int*)msI)[idx]));
    __syncthreads();

    // ---- layer 3: MFMA (M=4 live rows) ----
    #pragma unroll
    for (int nt2 = 0; nt2 < 2; nt2++) {
        const int ntg = wv * 2 + nt2;
        const float b3v = bf2f(b3[ntg * 16 + l15]);
        f32x4 c = {0.f, 0.f, 0.f, 0.f};
        #pragma unroll
        for (int ks = 0; ks < 4; ks++) {
            short8 a = *(const short8*)&msb[l15][ks * 32 + quad * 8];
            short8 b = *(const short8*)&w3s[(((size_t)(ntg * 4 + ks)) * 64 + lane) * 8];
            c = __builtin_amdgcn_mfma_f32_16x16x32_bf16(a, b, c, 0, 0, 0);
        }
        #pragma unroll
        for (int r = 0; r < 4; r++) {
            const int row = quad * 4 + r;
            if (row < NT)
                out[(size_t)(n0 + row) * HD + ntg * 16 + l15] = f2bf(fmaxf(c[r] + b3v, 0.f));
        }
    }
}

// ---------------------------------------------------------------------------
// Block-per-node mean aggregation (round-5-proven): 128 threads, coalesced
// 256B(bf16)/512B(f32) row reads, LDS-staged column indices.
// agg2: merged ll (blocks 0..19999, bf16 src) + aa (20000..23999, bf16 src).
// ---------------------------------------------------------------------------
__global__ __launch_bounds__(128) void agg2_kernel(
    const u16* __restrict__ lane_enc, const u16* __restrict__ agent_enc,
    const u16* __restrict__ col_ll, const int* __restrict__ rp_ll,
    const u16* __restrict__ col_aa, const int* __restrict__ rp_aa,
    float* __restrict__ out_lane, float* __restrict__ out_agent)
{
    __shared__ int cbuf[128];
    const u16* src; const u16* col; const int* rp; float* outp; int d;
    if (blockIdx.x < N_LANEC) { src = lane_enc; col = col_ll; rp = rp_ll; outp = out_lane; d = blockIdx.x; }
    else { src = agent_enc; col = col_aa; rp = rp_aa; outp = out_agent; d = blockIdx.x - N_LANEC; }
    const int j = threadIdx.x;
    const int beg = rp[d], end = rp[d + 1];
    float acc = 0.f;
    for (int base = beg; base < end; base += 128) {
        const int m = min(128, end - base);
        if (j < m) cbuf[j] = (int)col[base + j];
        __syncthreads();
        #pragma unroll 4
        for (int e = 0; e < m; e++)
            acc += bf2f(src[(size_t)cbuf[e] * HD + j]);
        __syncthreads();
    }
    outp[(size_t)d * HD + j] = acc / fmaxf((float)(end - beg), 1.f);
}

__global__ __launch_bounds__(128) void agg_la_kernel(
    const float* __restrict__ src, const u16* __restrict__ col,
    const int* __restrict__ rp, float* __restrict__ outp)
{
    __shared__ int cbuf[128];
    const int d = blockIdx.x;
    const int j = threadIdx.x;
    const int beg = rp[d], end = rp[d + 1];
    float acc = 0.f;
    for (int base = beg; base < end; base += 128) {
        const int m = min(128, end - base);
        if (j < m) cbuf[j] = (int)col[base + j];
        __syncthreads();
        #pragma unroll 4
        for (int e = 0; e < m; e++)
            acc += src[(size_t)cbuf[e] * HD + j];
        __syncthreads();
    }
    outp[(size_t)d * HD + j] = acc / fmaxf((float)(end - beg), 1.f);
}

// ---------------------------------------------------------------------------
// Edge GNN MLP body (MFMA): out = node + relu(relu([node,agg]@w1+b1)@w2+b2)
// node bf16, agg fp32 (may alias out). In-place safe: block reads only its
// own rows before its final writes. Weights pre-swizzled, biases bf16.
// ---------------------------------------------------------------------------
__device__ __forceinline__ void gnn_body(
    int n0, const u16* node, const float* agg,
    const u16* w1s, const u16* b1, const u16* w2s, const u16* b2,
    void* outv, int out_bf16)
{
    __shared__ __align__(16) u16 cats[16][2 * HD + 8];
    __shared__ __align__(16) u16 hb[16][HD + 8];
    const int tid  = threadIdx.x;
    const int lane = tid & 63;
    const int wv   = tid >> 6;
    const int l15  = lane & 15;
    const int quad = lane >> 4;

    const u32* node32 = (const u32*)node;
    const float2* agg2 = (const float2*)agg;
    for (int idx = tid; idx < 16 * 64; idx += 256) {
        int nn = idx >> 6, k2 = idx & 63;
        *(u32*)&cats[nn][k2 * 2] = node32[(size_t)(n0 + nn) * 64 + k2];
        float2 v = agg2[(size_t)(n0 + nn) * 64 + k2];
        *(u32*)&cats[nn][HD + k2 * 2] = ((u32)f2bf(v.y) << 16) | (u32)f2bf(v.x);
    }
    __syncthreads();

    // ---- layer 1: K=256 ----
    #pragma unroll
    for (int nt2 = 0; nt2 < 2; nt2++) {
        const int ntg = wv * 2 + nt2;
        const float b1v = bf2f(b1[ntg * 16 + l15]);
        f32x4 c = {0.f, 0.f, 0.f, 0.f};
        #pragma unroll
        for (int ks = 0; ks < 8; ks++) {
            short8 a = *(const short8*)&cats[l15][ks * 32 + quad * 8];
            short8 b = *(const short8*)&w1s[(((size_t)(ntg * 8 + ks)) * 64 + lane) * 8];
            c = __builtin_amdgcn_mfma_f32_16x16x32_bf16(a, b, c, 0, 0, 0);
        }
        #pragma unroll
        for (int r = 0; r < 4; r++)
            hb[quad * 4 + r][ntg * 16 + l15] = f2bf(fmaxf(c[r] + b1v, 0.f));
    }
    __syncthreads();

    // ---- layer 2: K=128, residual epilogue ----
    #pragma unroll
    for (int nt2 = 0; nt2 < 2; nt2++) {
        const int ntg = wv * 2 + nt2;
        const float b2v = bf2f(b2[ntg * 16 + l15]);
        f32x4 c = {0.f, 0.f, 0.f, 0.f};
        #pragma unroll
        for (int ks = 0; ks < 4; ks++) {
            short8 a = *(const short8*)&hb[l15][ks * 32 + quad * 8];
            short8 b = *(const short8*)&w2s[(((size_t)(ntg * 4 + ks)) * 64 + lane) * 8];
            c = __builtin_amdgcn_mfma_f32_16x16x32_bf16(a, b, c, 0, 0, 0);
        }
        #pragma unroll
        for (int r = 0; r < 4; r++) {
            const int row = quad * 4 + r;
            const int cidx = ntg * 16 + l15;
            size_t o = (size_t)(n0 + row) * HD + cidx;
            float res = bf2f(node[o]) + fmaxf(c[r] + b2v, 0.f);
            if (out_bf16) ((u16*)outv)[o] = f2bf(res);
            else          ((float*)outv)[o] = res;
        }
    }
}

struct Gnn2Args {
    const u16* node_ll; const float* agg_ll;
    const u16 *w1_ll, *b1_ll, *w2_ll, *b2_ll; float* out_ll;
    const u16* node_aa; const float* agg_aa;
    const u16 *w1_aa, *b1_aa, *w2_aa, *b2_aa; u16* out_aa;
};
__global__ __launch_bounds__(256) void gnn2_kernel(Gnn2Args a) {
    const int isL = (blockIdx.x < N_LANEC / 16);
    if (isL)
        gnn_body(blockIdx.x * 16, a.node_ll, a.agg_ll, a.w1_ll, a.b1_ll,
                 a.w2_ll, a.b2_ll, a.out_ll, 0);
    else
        gnn_body((blockIdx.x - N_LANEC / 16) * 16, a.node_aa, a.agg_aa,
                 a.w1_aa, a.b1_aa, a.w2_aa, a.b2_aa, a.out_aa, 1);
}
__global__ __launch_bounds__(256) void gnn_la_kernel(
    const u16* node, const float* agg,
    const u16* w1s, const u16* b1, const u16* w2s, const u16* b2, float* out) {
    gnn_body(blockIdx.x * 16, node, agg, w1s, b1, w2s, b2, out, 0);
}

// ---------------------------------------------------------------------------
// CSR build: zero, fused count, shfl-scan (emits cursors), fused fill
// ---------------------------------------------------------------------------
__global__ void zero_kernel(int* __restrict__ p, int n) {
    int i = blockIdx.x * blockDim.x + threadIdx.x;
    if (i < n) p[i] = 0;
}
__global__ void count_all_kernel(const int* __restrict__ e_ll, const int* __restrict__ e_aa,
                                 const int* __restrict__ e_la,
                                 int* __restrict__ rp_ll, int* __restrict__ rp_aa,
                                 int* __restrict__ rp_la) {
    int e = blockIdx.x * blockDim.x + threadIdx.x;
    if (e < E_LLC) atomicAdd(&rp_ll[e_ll[E_LLC + e]], 1);
    else if (e < E_LLC + E_AAC) atomicAdd(&rp_aa[e_aa[E_AAC + (e - E_LLC)]], 1);
    else if (e < E_LLC + E_AAC + E_LAC) atomicAdd(&rp_la[e_la[E_LAC + (e - E_LLC - E_AAC)]], 1);
}
__global__ void fill_all_kernel(const int* __restrict__ e_ll, const int* __restrict__ e_aa,
                                const int* __restrict__ e_la, int* __restrict__ cur,
                                u16* __restrict__ col_ll, u16* __restrict__ col_aa,
                                u16* __restrict__ col_la) {
    int e = blockIdx.x * blockDim.x + threadIdx.x;
    if (e < E_LLC) {
        int p = atomicAdd(&cur[e_ll[E_LLC + e]], 1);
        col_ll[p] = (u16)e_ll[e];
    } else if (e < E_LLC + E_AAC) {
        int i = e - E_LLC;
        int p = atomicAdd(&cur[N_LANEC + e_aa[E_AAC + i]], 1);
        col_aa[p] = (u16)e_aa[i];
    } else if (e < E_LLC + E_AAC + E_LAC) {
        int i = e - E_LLC - E_AAC;
        int p = atomicAdd(&cur[N_LANEC + N_AGENTC + e_la[E_LAC + i]], 1);
        col_la[p] = (u16)e_la[i];
    }
}

// shfl-based in-place exclusive scan; 3 barriers/chunk (vs 20 Hillis-Steele)
__global__ __launch_bounds__(1024) void scan3_kernel(
    int* __restrict__ rp_ll, int* __restrict__ rp_aa, int* __restrict__ rp_la,
    int* __restrict__ cur)
{
    int* rp; int n; int coff;
    if (blockIdx.x == 0)      { rp = rp_ll; n = N_LANEC; coff = 0; }
    else if (blockIdx.x == 1) { rp = rp_aa; n = N_AGENTC; coff = N_LANEC; }
    else                      { rp = rp_la; n = N_AGENTC; coff = N_LANEC + N_AGENTC; }

    __shared__ int wsum[16], wexcl[16];
    __shared__ int tot, carry;
    const int tid = threadIdx.x;
    const int lane = tid & 63, wid = tid >> 6;
    if (tid == 0) carry = 0;

    for (int base = 0; base < n; base += 1024) {
        const int i = base + tid;
        const int v = (i < n) ? rp[i] : 0;
        int incl = v;
        #pragma unroll
        for (int d = 1; d < 64; d <<= 1) {
            int t = __shfl_up(incl, (unsigned)d, 64);
            if (lane >= d) incl += t;
        }
        if (lane == 63) wsum[wid] = incl;
        __syncthreads();                       // barrier 1: wsum ready (+carry from prev chunk)
        if (wid == 0 && lane < 16) {
            int w = wsum[lane];
            int winc = w;
            #pragma unroll
            for (int d = 1; d < 16; d <<= 1) {
                int t = __shfl_up(winc, (unsigned)d, 64);
                if (lane >= d) winc += t;
            }
            wexcl[lane] = winc - w;
            if (lane == 15) tot = winc;
        }
        __syncthreads();                       // barrier 2: wexcl/tot ready
        const int c = carry;
        const int ex = c + wexcl[wid] + (incl - v);
        if (i < n) { rp[i] = ex; cur[coff + i] = ex; }
        __syncthreads();                       // barrier 3: all read carry
        if (tid == 0) carry = c + tot;
    }
    __syncthreads();
    if (tid == 0) rp[n] = carry;
}

// ---------------------------------------------------------------------------
extern "C" void kernel_launch(void* const* d_in, const int* in_sizes, int n_in,
                              void* d_out, int out_size, void* d_ws, size_t ws_size,
                              hipStream_t stream)
{
    const void* lane_pts   = d_in[0];
    const void* agent_hist = d_in[1];
    const int* e_ll = (const int*)d_in[2];   // [2][E]: row0 src, row1 dst
    const int* e_aa = (const int*)d_in[3];
    const int* e_la = (const int*)d_in[4];
    const void *lw1 = d_in[5],  *lb1 = d_in[6],  *lw2 = d_in[7],  *lb2 = d_in[8],
               *lw3 = d_in[9],  *lb3 = d_in[10];
    const void *aw1 = d_in[11], *ab1 = d_in[12], *aw2 = d_in[13], *ab2 = d_in[14],
               *aw3 = d_in[15], *ab3 = d_in[16];
    const void *llw1 = d_in[17], *llb1 = d_in[18], *llw2 = d_in[19], *llb2 = d_in[20];
    const void *aaw1 = d_in[21], *aab1 = d_in[22], *aaw2 = d_in[23], *aab2 = d_in[24];
    const void *law1 = d_in[25], *lab1 = d_in[26], *law2 = d_in[27], *lab2 = d_in[28];

    // ---- workspace layout (~9.8 MB) ----
    u16* sp = (u16*)d_ws;
    u16* swzbase = sp; sp += SWZ_TOTAL;
    u16* lw2s  = swzbase + 0;
    u16* aw2s  = swzbase + 16384;
    u16* lw3s  = swzbase + 32768;
    u16* aw3s  = swzbase + 49152;
    u16* llw1s = swzbase + 65536;
    u16* llw2s = swzbase + 98304;
    u16* aaw1s = swzbase + 114688;
    u16* aaw2s = swzbase + 147456;
    u16* law1s = swzbase + 163840;
    u16* law2s = swzbase + 196608;
    u16* lw1b  = swzbase + 212992;
    u16* aw1b  = swzbase + 214016;
    u16* lb1b  = swzbase + 215040;
    u16* lb2b  = swzbase + 215168;
    u16* lb3b  = swzbase + 215296;
    u16* ab1b  = swzbase + 215424;
    u16* ab2b  = swzbase + 215552;
    u16* ab3b  = swzbase + 215680;
    u16* llb1b = swzbase + 215808;
    u16* llb2b = swzbase + 215936;
    u16* aab1b = swzbase + 216064;
    u16* aab2b = swzbase + 216192;
    u16* lab1b = swzbase + 216320;
    u16* lab2b = swzbase + 216448;
    int* ip = (int*)sp;
    int* dflag = ip; ip += 4;
    int* rp_ll = ip; ip += N_LANEC + 1;
    int* rp_aa = ip; ip += N_AGENTC + 1;
    int* rp_la = ip; ip += N_AGENTC + 1;
    int* cur   = ip; ip += N_LANEC + 2 * N_AGENTC;
    u16* hp = (u16*)ip;
    u16* col_ll = hp; hp += E_LLC;
    u16* col_aa = hp; hp += E_AAC;
    u16* col_la = hp; hp += E_LAC;
    u16* lane_enc  = hp; hp += (size_t)N_LANEC * HD;
    u16* agent_enc = hp; hp += (size_t)N_AGENTC * HD;
    u16* agent_mid = hp; hp += (size_t)N_AGENTC * HD;

    float* out_lane  = (float*)d_out;
    float* out_agent = (float*)d_out + (size_t)N_LANEC * HD;

    const int NRP = (N_LANEC + 1) + 2 * (N_AGENTC + 1);
    const int NE_TOT = E_LLC + E_AAC + E_LAC;

    detect_kernel<<<1, 256, 0, stream>>>((const u32*)lane_pts, dflag);

    SwzSrc ss;
    ss.p[0] = lw2;  ss.p[1] = aw2;  ss.p[2] = lw3;  ss.p[3] = aw3;
    ss.p[4] = llw1; ss.p[5] = llw2; ss.p[6] = aaw1; ss.p[7] = aaw2;
    ss.p[8] = law1; ss.p[9] = law2;
    ss.p[10] = lw1; ss.p[11] = aw1;
    ss.p[12] = lb1; ss.p[13] = lb2; ss.p[14] = lb3;
    ss.p[15] = ab1; ss.p[16] = ab2; ss.p[17] = ab3;
    ss.p[18] = llb1; ss.p[19] = llb2; ss.p[20] = aab1; ss.p[21] = aab2;
    ss.p[22] = lab1; ss.p[23] = lab2;
    swz_all_kernel<<<(SWZ_TOTAL + 255) / 256, 256, 0, stream>>>(ss, swzbase, dflag);

    // ---- CSR build ----
    zero_kernel<<<(NRP + 255) / 256, 256, 0, stream>>>(rp_ll, NRP);
    count_all_kernel<<<(NE_TOT + 255) / 256, 256, 0, stream>>>(e_ll, e_aa, e_la, rp_ll, rp_aa, rp_la);
    scan3_kernel<<<3, 1024, 0, stream>>>(rp_ll, rp_aa, rp_la, cur);
    fill_all_kernel<<<(NE_TOT + 255) / 256, 256, 0, stream>>>(e_ll, e_aa, e_la, cur, col_ll, col_aa, col_la);

    // ---- encoders (merged) ----
    EncArgs ea;
    ea.x0 = lane_pts; ea.x1 = agent_hist;
    ea.w1a = lw1b; ea.b1a = lb1b; ea.w2a = lw2s; ea.b2a = lb2b; ea.w3a = lw3s; ea.b3a = lb3b;
    ea.w1b = aw1b; ea.b1b = ab1b; ea.w2b = aw2s; ea.b2b = ab2b; ea.w3b = aw3s; ea.b3b = ab3b;
    ea.out0 = lane_enc; ea.out1 = agent_enc;
    encode_kernel<<<(N_LANEC + N_AGENTC) / 4, 256, 0, stream>>>(ea, dflag);

    // ---- ll + aa aggregation (merged), f32 into d_out regions ----
    agg2_kernel<<<N_LANEC + N_AGENTC, 128, 0, stream>>>(
        lane_enc, agent_enc, col_ll, rp_ll, col_aa, rp_aa, out_lane, out_agent);

    // ---- ll + aa GNN (merged): ll in-place f32 in d_out; aa bf16 -> agent_mid ----
    Gnn2Args ga;
    ga.node_ll = lane_enc;  ga.agg_ll = out_lane;
    ga.w1_ll = llw1s; ga.b1_ll = llb1b; ga.w2_ll = llw2s; ga.b2_ll = llb2b; ga.out_ll = out_lane;
    ga.node_aa = agent_enc; ga.agg_aa = out_agent;
    ga.w1_aa = aaw1s; ga.b1_aa = aab1b; ga.w2_aa = aaw2s; ga.b2_aa = aab2b; ga.out_aa = agent_mid;
    gnn2_kernel<<<(N_LANEC + N_AGENTC) / 16, 256, 0, stream>>>(ga);

    // ---- lane->agent: agg from final lane (f32), gnn in-place into d_out ----
    agg_la_kernel<<<N_AGENTC, 128, 0, stream>>>(out_lane, col_la, rp_la, out_agent);
    gnn_la_kernel<<<N_AGENTC / 16, 256, 0, stream>>>(
        agent_mid, out_agent, law1s, lab1b, law2s, lab2b, out_agent);
}